// Round 1
// baseline (787.489 us; speedup 1.0000x reference)
//
#include <hip/hip_runtime.h>
#include <cstdint>

typedef unsigned short u16;
typedef __bf16 bf16x8 __attribute__((ext_vector_type(8)));
typedef float f32x4 __attribute__((ext_vector_type(4)));

#define GLOBAL_AS __attribute__((address_space(1)))
#define LDS_AS __attribute__((address_space(3)))

// ---------- helpers ----------
__device__ __forceinline__ u16 f2bf(float f) {
  unsigned u = __builtin_bit_cast(unsigned, f);
  u += 0x7FFFu + ((u >> 16) & 1u);   // RNE
  return (u16)(u >> 16);
}
__device__ __forceinline__ float bf2f(u16 h) {
  unsigned u = ((unsigned)h) << 16;
  return __builtin_bit_cast(float, u);
}
__device__ __forceinline__ void unpack2(unsigned u, float& a, float& b) {
  a = __builtin_bit_cast(float, u << 16);
  b = __builtin_bit_cast(float, u & 0xFFFF0000u);
}
__device__ __forceinline__ unsigned pk2(float a, float b) {
  return (unsigned)f2bf(a) | ((unsigned)f2bf(b) << 16);
}
__device__ __forceinline__ void gl_lds16(const void* g, void* l) {
  __builtin_amdgcn_global_load_lds((const GLOBAL_AS void*)g, (LDS_AS void*)l, 16, 0, 0);
}

// ---------- weight transpose fp32[K][N] -> bf16[N][K] ----------
__global__ __launch_bounds__(256) void transpose_w(const float* __restrict__ W,
                                                   u16* __restrict__ Wt, int K, int N) {
  __shared__ float tile[32][33];
  const int n0 = blockIdx.x * 32, k0 = blockIdx.y * 32;
  const int tx = threadIdx.x & 31, ty = threadIdx.x >> 5;
#pragma unroll
  for (int i = 0; i < 32; i += 8)
    tile[ty + i][tx] = W[(size_t)(k0 + ty + i) * N + n0 + tx];
  __syncthreads();
#pragma unroll
  for (int i = 0; i < 32; i += 8)
    Wt[(size_t)(n0 + ty + i) * K + k0 + tx] = f2bf(tile[tx][ty + i]);
}

// ---------- generic 128x128 bf16 MFMA GEMM, K=512 ----------
// A: M x 512 (bf16 ws, or fp32 when AF32), Bt: N x 512 bf16 (pre-transposed)
// MODE 0: outB = bf16(v+bias)                      (x1)
// MODE 1: outF = v+bias                            (t3 raw pre-LN)
// MODE 2: y=bn(v+bias); outF=y; outB=bf16(relu y)  (h1 / f_global)
// MODE 3: y=bn(v+bias); outB=bf16(relu y)          (h2)
// MODE 4: y=v+bias; outF=y; outB=bf16(y)           (f_cnn, AF32)
template <int MODE, bool AF32>
__global__ __launch_bounds__(256) void gemm_k(
    const float* __restrict__ Af, const u16* __restrict__ Ab,
    const u16* __restrict__ Bt, const float* __restrict__ bias,
    float* __restrict__ outF, u16* __restrict__ outB,
    const float* __restrict__ bng, const float* __restrict__ bnb, int N) {
  __shared__ __align__(16) u16 As[128 * 32];
  __shared__ __align__(16) u16 Bs[128 * 32];
  const int t = threadIdx.x;
  const int tn0 = blockIdx.x * 128, tm0 = blockIdx.y * 128;
  const int w = t >> 6, lane = t & 63;
  const int wm = w >> 1, wn = w & 1, lr = lane & 15, quad = lane >> 4;

  f32x4 acc[4][4];
#pragma unroll
  for (int i = 0; i < 4; ++i)
#pragma unroll
    for (int j = 0; j < 4; ++j) {
      acc[i][j][0] = 0.f; acc[i][j][1] = 0.f; acc[i][j][2] = 0.f; acc[i][j][3] = 0.f;
    }

  for (int kc = 0; kc < 16; ++kc) {
    const int kb = kc * 32;
    // B tile: 128 rows(n) x 32 k, direct-to-LDS 16B
    {
      const int c0 = t, c1 = t + 256;
      gl_lds16(Bt + (size_t)(tn0 + (c0 >> 2)) * 512 + kb + (c0 & 3) * 8, Bs + c0 * 8);
      gl_lds16(Bt + (size_t)(tn0 + (c1 >> 2)) * 512 + kb + (c1 & 3) * 8, Bs + c1 * 8);
    }
    if constexpr (AF32) {
      // stage fp32 A -> convert -> LDS
      const int row = t >> 1, half = t & 1;
      const float* g = Af + (size_t)(tm0 + row) * 512 + kb + half * 16;
      float4 q0 = ((const float4*)g)[0];
      float4 q1 = ((const float4*)g)[1];
      float4 q2 = ((const float4*)g)[2];
      float4 q3 = ((const float4*)g)[3];
      int4 s0 = make_int4(pk2(q0.x, q0.y), pk2(q0.z, q0.w), pk2(q1.x, q1.y), pk2(q1.z, q1.w));
      int4 s1 = make_int4(pk2(q2.x, q2.y), pk2(q2.z, q2.w), pk2(q3.x, q3.y), pk2(q3.z, q3.w));
      *(int4*)&As[row * 32 + half * 16] = s0;
      *(int4*)&As[row * 32 + half * 16 + 8] = s1;
    } else {
      const int c0 = t, c1 = t + 256;
      gl_lds16(Ab + (size_t)(tm0 + (c0 >> 2)) * 512 + kb + (c0 & 3) * 8, As + c0 * 8);
      gl_lds16(Ab + (size_t)(tm0 + (c1 >> 2)) * 512 + kb + (c1 & 3) * 8, As + c1 * 8);
    }
    __syncthreads();
    bf16x8 af[4], bfr[4];
#pragma unroll
    for (int mt = 0; mt < 4; ++mt)
      af[mt] = *(const bf16x8*)&As[(wm * 64 + mt * 16 + lr) * 32 + quad * 8];
#pragma unroll
    for (int nt = 0; nt < 4; ++nt)
      bfr[nt] = *(const bf16x8*)&Bs[(wn * 64 + nt * 16 + lr) * 32 + quad * 8];
#pragma unroll
    for (int mt = 0; mt < 4; ++mt)
#pragma unroll
      for (int nt = 0; nt < 4; ++nt)
        acc[mt][nt] = __builtin_amdgcn_mfma_f32_16x16x32_bf16(af[mt], bfr[nt], acc[mt][nt], 0, 0, 0);
    __syncthreads();
  }

  const float BNS = 0.9999950000374998f;  // 1/sqrt(1+1e-5)
#pragma unroll
  for (int nt = 0; nt < 4; ++nt) {
    const int col = tn0 + wn * 64 + nt * 16 + lr;
    const float bs = bias[col];
    float g_ = 0.f, b_ = 0.f;
    if constexpr (MODE == 2 || MODE == 3) { g_ = bng[col] * BNS; b_ = bnb[col]; }
#pragma unroll
    for (int mt = 0; mt < 4; ++mt) {
      const int row0 = tm0 + wm * 64 + mt * 16 + quad * 4;
#pragma unroll
      for (int r = 0; r < 4; ++r) {
        const size_t idx = (size_t)(row0 + r) * N + col;
        const float v = acc[mt][nt][r] + bs;
        if constexpr (MODE == 0) {
          outB[idx] = f2bf(v);
        } else if constexpr (MODE == 1) {
          outF[idx] = v;
        } else if constexpr (MODE == 2) {
          const float y = v * g_ + b_;
          outF[idx] = y;
          outB[idx] = f2bf(fmaxf(y, 0.f));
        } else if constexpr (MODE == 3) {
          const float y = v * g_ + b_;
          outB[idx] = f2bf(fmaxf(y, 0.f));
        } else {
          outF[idx] = v;
          outB[idx] = f2bf(v);
        }
      }
    }
  }
}

// ---------- fused per-batch: layernorm(x1) -> f_vit1, att, maxpool -> fv2raw ----------
__global__ __launch_bounds__(256) void fuse_ln_att_max(
    const u16* __restrict__ x1, const float* __restrict__ g, const float* __restrict__ bb,
    const float* __restrict__ Wa, const float* __restrict__ ba,
    float* __restrict__ fv1, float* __restrict__ att, u16* __restrict__ fv2raw) {
  __shared__ __align__(16) u16 xs[20 * 512];
  const int b = blockIdx.x, t = threadIdx.x;
  const int4* src = (const int4*)(x1 + (size_t)b * 10240);
  int4* dst = (int4*)xs;
#pragma unroll
  for (int i = 0; i < 5; ++i) dst[t + 256 * i] = src[t + 256 * i];
  __syncthreads();
  const int w = t >> 6, lane = t & 63;
  const float inv512 = 1.0f / 512.0f;
  const float ba0 = ba[0];
  float gv[8], bv[8], wv[8];
#pragma unroll
  for (int e = 0; e < 8; ++e) {
    gv[e] = g[lane * 8 + e];
    bv[e] = bb[lane * 8 + e];
    wv[e] = Wa[lane * 8 + e];
  }
#pragma unroll
  for (int j = 0; j < 5; ++j) {
    const int v = w * 5 + j;
    int4 q = *(const int4*)&xs[v * 512 + lane * 8];
    float f[8];
    unpack2((unsigned)q.x, f[0], f[1]);
    unpack2((unsigned)q.y, f[2], f[3]);
    unpack2((unsigned)q.z, f[4], f[5]);
    unpack2((unsigned)q.w, f[6], f[7]);
    float s = 0.f, ss = 0.f;
#pragma unroll
    for (int e = 0; e < 8; ++e) { s += f[e]; ss += f[e] * f[e]; }
#pragma unroll
    for (int o = 32; o; o >>= 1) { s += __shfl_xor(s, o); ss += __shfl_xor(ss, o); }
    const float m = s * inv512;
    const float var = ss * inv512 - m * m;
    const float rs = rsqrtf(var + 1e-5f);
    float y[8], z = 0.f;
#pragma unroll
    for (int e = 0; e < 8; ++e) {
      y[e] = (f[e] - m) * rs * gv[e] + bv[e];
      z += y[e] * wv[e];
    }
    float* op = fv1 + ((size_t)b * 20 + v) * 512 + lane * 8;
    *(float4*)op = make_float4(y[0], y[1], y[2], y[3]);
    *(float4*)(op + 4) = make_float4(y[4], y[5], y[6], y[7]);
#pragma unroll
    for (int o = 32; o; o >>= 1) z += __shfl_xor(z, o);
    if (lane == 0) att[(size_t)b * 20 + v] = 1.f / (1.f + __expf(-(z + ba0)));
  }
  // maxpool over the 20 views
  for (int d = t; d < 512; d += 256) {
    float mx = -3.4e38f;
#pragma unroll
    for (int v = 0; v < 20; ++v) mx = fmaxf(mx, bf2f(xs[v * 512 + d]));
    fv2raw[(size_t)b * 512 + d] = f2bf(mx);
  }
}

// ---------- row-wise layernorm (4096 x 512 fp32 in) -> fp32 out + bf16 ws ----------
__global__ __launch_bounds__(256) void ln_rows(const float* __restrict__ in,
                                               const float* __restrict__ g,
                                               const float* __restrict__ bb,
                                               float* __restrict__ outF, u16* __restrict__ outB) {
  const int row = blockIdx.x * 4 + (threadIdx.x >> 6);
  const int lane = threadIdx.x & 63;
  const float* p = in + (size_t)row * 512 + lane * 8;
  float4 a = *(const float4*)p, c = *(const float4*)(p + 4);
  float f[8] = {a.x, a.y, a.z, a.w, c.x, c.y, c.z, c.w};
  float s = 0.f, ss = 0.f;
#pragma unroll
  for (int e = 0; e < 8; ++e) { s += f[e]; ss += f[e] * f[e]; }
#pragma unroll
  for (int o = 32; o; o >>= 1) { s += __shfl_xor(s, o); ss += __shfl_xor(ss, o); }
  const float m = s * (1.0f / 512.0f);
  const float rs = rsqrtf(ss * (1.0f / 512.0f) - m * m + 1e-5f);
  float y[8];
#pragma unroll
  for (int e = 0; e < 8; ++e) y[e] = (f[e] - m) * rs * g[lane * 8 + e] + bb[lane * 8 + e];
  float* op = outF + (size_t)row * 512 + lane * 8;
  *(float4*)op = make_float4(y[0], y[1], y[2], y[3]);
  *(float4*)(op + 4) = make_float4(y[4], y[5], y[6], y[7]);
  int4 ob = make_int4(pk2(y[0], y[1]), pk2(y[2], y[3]), pk2(y[4], y[5]), pk2(y[6], y[7]));
  *(int4*)(outB + (size_t)row * 512 + lane * 8) = ob;
}

// ---------- final small GEMM: [4096,256] bf16 @ [256,40] fp32 + bias ----------
__global__ __launch_bounds__(320) void pred_k(const u16* __restrict__ h2a,
                                              const float* __restrict__ W,
                                              const float* __restrict__ bias,
                                              float* __restrict__ out) {
  const int t = threadIdx.x;
  const int r = t / 40, n = t - r * 40;
  const size_t b = (size_t)blockIdx.x * 8 + r;
  const u16* hp = h2a + b * 256;
  float s = 0.f;
#pragma unroll 4
  for (int k0 = 0; k0 < 256; k0 += 8) {
    int4 q = *(const int4*)(hp + k0);
    float f0, f1, f2, f3, f4, f5, f6, f7;
    unpack2((unsigned)q.x, f0, f1);
    unpack2((unsigned)q.y, f2, f3);
    unpack2((unsigned)q.z, f4, f5);
    unpack2((unsigned)q.w, f6, f7);
    const float* wp = W + (size_t)k0 * 40 + n;
    s += f0 * wp[0] + f1 * wp[40] + f2 * wp[80] + f3 * wp[120] +
         f4 * wp[160] + f5 * wp[200] + f6 * wp[240] + f7 * wp[280];
  }
  out[b * 40 + n] = s + bias[n];
}

extern "C" void kernel_launch(void* const* d_in, const int* in_sizes, int n_in,
                              void* d_out, int out_size, void* d_ws, size_t ws_size,
                              hipStream_t stream) {
  (void)in_sizes; (void)n_in; (void)out_size; (void)ws_size;
  const float* x    = (const float*)d_in[0];
  const float* We   = (const float*)d_in[1];
  const float* be   = (const float*)d_in[2];
  const float* W1   = (const float*)d_in[3];
  const float* b1   = (const float*)d_in[4];
  const float* Wa   = (const float*)d_in[5];
  const float* ba   = (const float*)d_in[6];
  const float* W2   = (const float*)d_in[7];
  const float* b2   = (const float*)d_in[8];
  const float* ln_g = (const float*)d_in[9];
  const float* ln_b = (const float*)d_in[10];
  const float* h1W  = (const float*)d_in[11];
  const float* h1b  = (const float*)d_in[12];
  const float* bn1g = (const float*)d_in[13];
  const float* bn1b = (const float*)d_in[14];
  const float* h2W  = (const float*)d_in[15];
  const float* h2b  = (const float*)d_in[16];
  const float* bn2g = (const float*)d_in[17];
  const float* bn2b = (const float*)d_in[18];
  const float* h3W  = (const float*)d_in[19];
  const float* h3b  = (const float*)d_in[20];

  float* out = (float*)d_out;
  float* o_fcnn  = out;                    // 81920*512
  float* o_fvit1 = o_fcnn + 41943040;      // 81920*512
  float* o_att   = o_fvit1 + 41943040;     // 4096*20
  float* o_fvit2 = o_att + 81920;          // 4096*512
  float* o_fglob = o_fvit2 + 2097152;      // 4096*512
  float* o_pred  = o_fglob + 2097152;      // 4096*40

  // workspace layout (bf16 elements; all offsets 16B-aligned)
  u16* ws = (u16*)d_ws;
  u16* Wet   = ws;                 // 512*512
  u16* W1t   = Wet + 262144;       // 512*512
  u16* W2t   = W1t + 262144;       // 512*512
  u16* h1Wt  = W2t + 262144;       // 512*512
  u16* h2Wt  = h1Wt + 262144;      // 256*512
  u16* fcnnB = h2Wt + 131072;      // 81920*512
  u16* x1B   = fcnnB + 41943040;   // 81920*512
  u16* fv2rB = x1B + 41943040;     // 4096*512
  u16* fv2B  = fv2rB + 2097152;    // 4096*512
  u16* hrelB = fv2B + 2097152;     // 4096*512
  u16* h2aB  = hrelB + 2097152;    // 4096*256
  float* t3raw = (float*)(h2aB + 1048576);  // 4096*512 fp32

  const dim3 blk(256);
  // 1) transpose+cast weights (Wt[n][k] bf16 so B fragments are k-contiguous)
  transpose_w<<<dim3(16, 16), blk, 0, stream>>>(We, Wet, 512, 512);
  transpose_w<<<dim3(16, 16), blk, 0, stream>>>(W1, W1t, 512, 512);
  transpose_w<<<dim3(16, 16), blk, 0, stream>>>(W2, W2t, 512, 512);
  transpose_w<<<dim3(16, 16), blk, 0, stream>>>(h1W, h1Wt, 512, 512);
  transpose_w<<<dim3(8, 16), blk, 0, stream>>>(h2W, h2Wt, 512, 256);

  // 2) f_cnn = x @ We + be   (fp32 out + bf16 ws copy)
  gemm_k<4, true><<<dim3(4, 640), blk, 0, stream>>>(x, nullptr, Wet, be, o_fcnn, fcnnB,
                                                    nullptr, nullptr, 512);
  // 3) x1 = f_cnn @ W1 + b1  (bf16 ws)
  gemm_k<0, false><<<dim3(4, 640), blk, 0, stream>>>(nullptr, fcnnB, W1t, b1, nullptr, x1B,
                                                     nullptr, nullptr, 512);
  // 4) f_vit1 = LN(x1), att = sigmoid(f_vit1@Wa+ba), fv2raw = max over views
  fuse_ln_att_max<<<dim3(4096), blk, 0, stream>>>(x1B, ln_g, ln_b, Wa, ba, o_fvit1, o_att, fv2rB);
  // 5) t3raw = fv2raw @ W2 + b2
  gemm_k<1, false><<<dim3(4, 32), blk, 0, stream>>>(nullptr, fv2rB, W2t, b2, t3raw, nullptr,
                                                    nullptr, nullptr, 512);
  // 6) f_vit2 = LN(t3raw)
  ln_rows<<<dim3(1024), blk, 0, stream>>>(t3raw, ln_g, ln_b, o_fvit2, fv2B);
  // 7) f_global = bn1(f_vit2 @ h1W + h1b); hrelu = relu(f_global)
  gemm_k<2, false><<<dim3(4, 32), blk, 0, stream>>>(nullptr, fv2B, h1Wt, h1b, o_fglob, hrelB,
                                                    bn1g, bn1b, 512);
  // 8) h2 = relu(bn2(hrelu @ h2W + h2b))   (N=256)
  gemm_k<3, false><<<dim3(2, 32), blk, 0, stream>>>(nullptr, hrelB, h2Wt, h2b, nullptr, h2aB,
                                                    bn2g, bn2b, 256);
  // 9) pred = h2 @ h3W + h3b
  pred_k<<<dim3(512), dim3(320), 0, stream>>>(h2aB, h3W, h3b, o_pred);
}

// Round 5
// 764.536 us; speedup vs baseline: 1.0300x; 1.0300x over previous
//
#include <hip/hip_runtime.h>
#include <cstdint>

typedef unsigned short u16;
typedef __bf16 bf16x8 __attribute__((ext_vector_type(8)));
typedef float f32x4 __attribute__((ext_vector_type(4)));

#define GLOBAL_AS __attribute__((address_space(1)))
#define LDS_AS __attribute__((address_space(3)))

// ---------- helpers ----------
__device__ __forceinline__ u16 f2bf(float f) {
  unsigned u = __builtin_bit_cast(unsigned, f);
  u += 0x7FFFu + ((u >> 16) & 1u);   // RNE
  return (u16)(u >> 16);
}
__device__ __forceinline__ float bf2f(u16 h) {
  unsigned u = ((unsigned)h) << 16;
  return __builtin_bit_cast(float, u);
}
__device__ __forceinline__ void unpack2(unsigned u, float& a, float& b) {
  a = __builtin_bit_cast(float, u << 16);
  b = __builtin_bit_cast(float, u & 0xFFFF0000u);
}
__device__ __forceinline__ unsigned pk2(float a, float b) {
  return (unsigned)f2bf(a) | ((unsigned)f2bf(b) << 16);
}
__device__ __forceinline__ void gl_lds16(const void* g, void* l) {
  __builtin_amdgcn_global_load_lds((const GLOBAL_AS void*)g, (LDS_AS void*)l, 16, 0, 0);
}

// ---------- weight transpose fp32[K][N] -> bf16[N][K] ----------
__global__ __launch_bounds__(256) void transpose_w(const float* __restrict__ W,
                                                   u16* __restrict__ Wt, int K, int N) {
  __shared__ float tile[32][33];
  const int n0 = blockIdx.x * 32, k0 = blockIdx.y * 32;
  const int tx = threadIdx.x & 31, ty = threadIdx.x >> 5;
#pragma unroll
  for (int i = 0; i < 32; i += 8)
    tile[ty + i][tx] = W[(size_t)(k0 + ty + i) * N + n0 + tx];
  __syncthreads();
#pragma unroll
  for (int i = 0; i < 32; i += 8)
    Wt[(size_t)(n0 + ty + i) * K + k0 + tx] = f2bf(tile[tx][ty + i]);
}

// ---------- bc = b1 + be @ W1 ----------
__global__ __launch_bounds__(128) void bias_c(const float* __restrict__ be,
                                              const float* __restrict__ W1,
                                              const float* __restrict__ b1,
                                              float* __restrict__ bc) {
  const int n = blockIdx.x * 128 + threadIdx.x;
  float s = b1[n];
  for (int k = 0; k < 512; ++k) s += be[k] * W1[(size_t)k * 512 + n];
  bc[n] = s;
}

// ---------- generic dbuf MFMA GEMM, K=512, tile (32*FM) x (32*FN) ----------
// MODE 1: outF = v+bias
// MODE 2: y=bn(v+bias); outF=y; outB=bf16(relu y)
// MODE 3: y=bn(v+bias); outB=bf16(relu y)
// MODE 7: outB[col*N + row] = bf16(v)   (transposed store, no bias; AF32)
template <int MODE, int FM, int FN, bool AF32>
__global__ __launch_bounds__(256) void gemm_k2(
    const float* __restrict__ Af, const u16* __restrict__ Ab,
    const u16* __restrict__ Bt, const float* __restrict__ bias,
    float* __restrict__ outF, u16* __restrict__ outB,
    const float* __restrict__ bng, const float* __restrict__ bnb, int N) {
  constexpr int TM = 32 * FM, TN = 32 * FN;
  __shared__ __align__(16) u16 As[2][TM * 32];
  __shared__ __align__(16) u16 Bs[2][TN * 32];
  const int t = threadIdx.x;
  const int tn0 = blockIdx.x * TN, tm0 = blockIdx.y * TM;
  const int w = t >> 6, lane = t & 63;
  const int wm = w >> 1, wn = w & 1, lr = lane & 15, quad = lane >> 4;

  f32x4 acc[FM][FN];
#pragma unroll
  for (int i = 0; i < FM; ++i)
#pragma unroll
    for (int j = 0; j < FN; ++j) {
      acc[i][j][0] = 0.f; acc[i][j][1] = 0.f; acc[i][j][2] = 0.f; acc[i][j][3] = 0.f;
    }

  float4 aq[4];
  auto stage = [&](int buf, int kb) {
#pragma unroll
    for (int i = 0; i < TN / 64; ++i) {
      const int c = t + 256 * i;
      gl_lds16(Bt + (size_t)(tn0 + (c >> 2)) * 512 + kb + (c & 3) * 8, &Bs[buf][c * 8]);
    }
    if constexpr (!AF32) {
#pragma unroll
      for (int i = 0; i < TM / 64; ++i) {
        const int c = t + 256 * i;
        gl_lds16(Ab + (size_t)(tm0 + (c >> 2)) * 512 + kb + (c & 3) * 8, &As[buf][c * 8]);
      }
    }
  };
  auto loadA = [&](int kb) {   // AF32 only (FM==4)
    const int row = t >> 1, half = t & 1;
    const float* g = Af + (size_t)(tm0 + row) * 512 + kb + half * 16;
    aq[0] = ((const float4*)g)[0]; aq[1] = ((const float4*)g)[1];
    aq[2] = ((const float4*)g)[2]; aq[3] = ((const float4*)g)[3];
  };
  auto writeA = [&](int buf) {  // XOR-swizzled (write+read sides both in-kernel)
    const int row = t >> 1, half = t & 1;
    int4 s0 = make_int4(pk2(aq[0].x, aq[0].y), pk2(aq[0].z, aq[0].w),
                        pk2(aq[1].x, aq[1].y), pk2(aq[1].z, aq[1].w));
    int4 s1 = make_int4(pk2(aq[2].x, aq[2].y), pk2(aq[2].z, aq[2].w),
                        pk2(aq[3].x, aq[3].y), pk2(aq[3].z, aq[3].w));
    const int m = (row & 7) << 3;
    *(int4*)&As[buf][(row * 32 + half * 16) ^ m] = s0;
    *(int4*)&As[buf][(row * 32 + half * 16 + 8) ^ m] = s1;
  };

  if constexpr (AF32) { loadA(0); writeA(0); }
  stage(0, 0);
  __syncthreads();

  for (int kc = 0; kc < 16; ++kc) {
    const int cur = kc & 1;
    if (kc < 15) {
      if constexpr (AF32) loadA(kc * 32 + 32);
      stage(cur ^ 1, kc * 32 + 32);
    }
    bf16x8 af[FM], bfr[FN];
#pragma unroll
    for (int mt = 0; mt < FM; ++mt) {
      const int ar = wm * (TM / 2) + mt * 16 + lr;
      const int idx = AF32 ? ((ar * 32 + quad * 8) ^ ((ar & 7) << 3)) : (ar * 32 + quad * 8);
      af[mt] = *(const bf16x8*)&As[cur][idx];
    }
#pragma unroll
    for (int nt = 0; nt < FN; ++nt)
      bfr[nt] = *(const bf16x8*)&Bs[cur][(wn * (TN / 2) + nt * 16 + lr) * 32 + quad * 8];
#pragma unroll
    for (int mt = 0; mt < FM; ++mt)
#pragma unroll
      for (int nt = 0; nt < FN; ++nt)
        acc[mt][nt] = __builtin_amdgcn_mfma_f32_16x16x32_bf16(af[mt], bfr[nt], acc[mt][nt], 0, 0, 0);
    if (kc < 15) {
      if constexpr (AF32) writeA(cur ^ 1);
    }
    __syncthreads();
  }

  const float BNS = 0.9999950000374998f;  // 1/sqrt(1+1e-5)
#pragma unroll
  for (int nt = 0; nt < FN; ++nt) {
    const int col = tn0 + wn * (TN / 2) + nt * 16 + lr;
    float bs = 0.f, g_ = 0.f, b_ = 0.f;
    if constexpr (MODE != 7) bs = bias[col];
    if constexpr (MODE == 2 || MODE == 3) { g_ = bng[col] * BNS; b_ = bnb[col]; }
#pragma unroll
    for (int mt = 0; mt < FM; ++mt) {
      const int row0 = tm0 + wm * (TM / 2) + mt * 16 + quad * 4;
#pragma unroll
      for (int r = 0; r < 4; ++r) {
        const float v = acc[mt][nt][r] + bs;
        if constexpr (MODE == 1) {
          outF[(size_t)(row0 + r) * N + col] = v;
        } else if constexpr (MODE == 2) {
          const float y = v * g_ + b_;
          const size_t idx = (size_t)(row0 + r) * N + col;
          outF[idx] = y;
          outB[idx] = f2bf(fmaxf(y, 0.f));
        } else if constexpr (MODE == 3) {
          const float y = v * g_ + b_;
          outB[(size_t)(row0 + r) * N + col] = f2bf(fmaxf(y, 0.f));
        } else {  // MODE 7: transposed bf16 store (Wc^T)
          outB[(size_t)col * N + (row0 + r)] = f2bf(v);
        }
      }
    }
  }
}

// ---------- fused dual GEMM: f_cnn = x@We+be (fp32), x1 = x@Wc+bc (bf16) ----------
__global__ __launch_bounds__(256) void gemm_x2(
    const float* __restrict__ x, const u16* __restrict__ B1t, const u16* __restrict__ B2t,
    const float* __restrict__ b1v, const float* __restrict__ b2v,
    float* __restrict__ outF, u16* __restrict__ outB) {
  __shared__ __align__(16) u16 As[2][128 * 32];
  __shared__ __align__(16) u16 B1s[2][128 * 32];
  __shared__ __align__(16) u16 B2s[2][128 * 32];
  const int t = threadIdx.x;
  // XCD-chunk swizzle: grid = 4 x 640 = 2560 = 8*320 (bijective)
  int bid = blockIdx.y * 4 + blockIdx.x;
  bid = (bid & 7) * 320 + (bid >> 3);
  const int tn0 = (bid & 3) * 128, tm0 = (bid >> 2) * 128;
  const int w = t >> 6, lane = t & 63;
  const int wm = w >> 1, wn = w & 1, lr = lane & 15, quad = lane >> 4;

  f32x4 acc0[4][4], acc1[4][4];
#pragma unroll
  for (int i = 0; i < 4; ++i)
#pragma unroll
    for (int j = 0; j < 4; ++j) {
      acc0[i][j][0] = 0.f; acc0[i][j][1] = 0.f; acc0[i][j][2] = 0.f; acc0[i][j][3] = 0.f;
      acc1[i][j][0] = 0.f; acc1[i][j][1] = 0.f; acc1[i][j][2] = 0.f; acc1[i][j][3] = 0.f;
    }

  float4 aq[4];
  auto stageB = [&](int buf, int kb) {
#pragma unroll
    for (int i = 0; i < 2; ++i) {
      const int c = t + 256 * i;
      const size_t go = (size_t)(tn0 + (c >> 2)) * 512 + kb + (c & 3) * 8;
      gl_lds16(B1t + go, &B1s[buf][c * 8]);
      gl_lds16(B2t + go, &B2s[buf][c * 8]);
    }
  };
  auto loadA = [&](int kb) {
    const int row = t >> 1, half = t & 1;
    const float* g = x + (size_t)(tm0 + row) * 512 + kb + half * 16;
    aq[0] = ((const float4*)g)[0]; aq[1] = ((const float4*)g)[1];
    aq[2] = ((const float4*)g)[2]; aq[3] = ((const float4*)g)[3];
  };
  auto writeA = [&](int buf) {
    const int row = t >> 1, half = t & 1;
    int4 s0 = make_int4(pk2(aq[0].x, aq[0].y), pk2(aq[0].z, aq[0].w),
                        pk2(aq[1].x, aq[1].y), pk2(aq[1].z, aq[1].w));
    int4 s1 = make_int4(pk2(aq[2].x, aq[2].y), pk2(aq[2].z, aq[2].w),
                        pk2(aq[3].x, aq[3].y), pk2(aq[3].z, aq[3].w));
    const int m = (row & 7) << 3;
    *(int4*)&As[buf][(row * 32 + half * 16) ^ m] = s0;
    *(int4*)&As[buf][(row * 32 + half * 16 + 8) ^ m] = s1;
  };

  loadA(0); writeA(0); stageB(0, 0);
  __syncthreads();

  for (int kc = 0; kc < 16; ++kc) {
    const int cur = kc & 1;
    if (kc < 15) {
      loadA(kc * 32 + 32);
      stageB(cur ^ 1, kc * 32 + 32);
    }
    bf16x8 af[4];
#pragma unroll
    for (int mt = 0; mt < 4; ++mt) {
      const int ar = wm * 64 + mt * 16 + lr;
      af[mt] = *(const bf16x8*)&As[cur][(ar * 32 + quad * 8) ^ ((ar & 7) << 3)];
    }
#pragma unroll
    for (int nt = 0; nt < 4; ++nt) {
      const int bi = (wn * 64 + nt * 16 + lr) * 32 + quad * 8;
      bf16x8 b1 = *(const bf16x8*)&B1s[cur][bi];
#pragma unroll
      for (int mt = 0; mt < 4; ++mt)
        acc0[mt][nt] = __builtin_amdgcn_mfma_f32_16x16x32_bf16(af[mt], b1, acc0[mt][nt], 0, 0, 0);
      bf16x8 b2 = *(const bf16x8*)&B2s[cur][bi];
#pragma unroll
      for (int mt = 0; mt < 4; ++mt)
        acc1[mt][nt] = __builtin_amdgcn_mfma_f32_16x16x32_bf16(af[mt], b2, acc1[mt][nt], 0, 0, 0);
    }
    if (kc < 15) writeA(cur ^ 1);
    __syncthreads();
  }

#pragma unroll
  for (int nt = 0; nt < 4; ++nt) {
    const int col = tn0 + wn * 64 + nt * 16 + lr;
    const float bsE = b1v[col], bsC = b2v[col];
#pragma unroll
    for (int mt = 0; mt < 4; ++mt) {
      const int row0 = tm0 + wm * 64 + mt * 16 + quad * 4;
#pragma unroll
      for (int r = 0; r < 4; ++r) {
        const size_t idx = (size_t)(row0 + r) * 512 + col;
        outF[idx] = acc0[mt][nt][r] + bsE;
        outB[idx] = f2bf(acc1[mt][nt][r] + bsC);
      }
    }
  }
}

// ---------- fused per-batch: layernorm(x1) -> f_vit1, att, maxpool -> fv2raw ----------
__global__ __launch_bounds__(256) void fuse_ln_att_max(
    const u16* __restrict__ x1, const float* __restrict__ g, const float* __restrict__ bb,
    const float* __restrict__ Wa, const float* __restrict__ ba,
    float* __restrict__ fv1, float* __restrict__ att, u16* __restrict__ fv2raw) {
  __shared__ __align__(16) u16 xs[20 * 512];
  const int b = blockIdx.x, t = threadIdx.x;
  const int4* src = (const int4*)(x1 + (size_t)b * 10240);
  int4* dst = (int4*)xs;
#pragma unroll
  for (int i = 0; i < 5; ++i) dst[t + 256 * i] = src[t + 256 * i];
  __syncthreads();
  const int w = t >> 6, lane = t & 63;
  const float inv512 = 1.0f / 512.0f;
  const float ba0 = ba[0];
  float gv[8], bv[8], wv[8];
#pragma unroll
  for (int e = 0; e < 8; ++e) {
    gv[e] = g[lane * 8 + e];
    bv[e] = bb[lane * 8 + e];
    wv[e] = Wa[lane * 8 + e];
  }
#pragma unroll
  for (int j = 0; j < 5; ++j) {
    const int v = w * 5 + j;
    int4 q = *(const int4*)&xs[v * 512 + lane * 8];
    float f[8];
    unpack2((unsigned)q.x, f[0], f[1]);
    unpack2((unsigned)q.y, f[2], f[3]);
    unpack2((unsigned)q.z, f[4], f[5]);
    unpack2((unsigned)q.w, f[6], f[7]);
    float s = 0.f, ss = 0.f;
#pragma unroll
    for (int e = 0; e < 8; ++e) { s += f[e]; ss += f[e] * f[e]; }
#pragma unroll
    for (int o = 32; o; o >>= 1) { s += __shfl_xor(s, o); ss += __shfl_xor(ss, o); }
    const float m = s * inv512;
    const float var = ss * inv512 - m * m;
    const float rs = rsqrtf(var + 1e-5f);
    float y[8], z = 0.f;
#pragma unroll
    for (int e = 0; e < 8; ++e) {
      y[e] = (f[e] - m) * rs * gv[e] + bv[e];
      z += y[e] * wv[e];
    }
    float* op = fv1 + ((size_t)b * 20 + v) * 512 + lane * 8;
    *(float4*)op = make_float4(y[0], y[1], y[2], y[3]);
    *(float4*)(op + 4) = make_float4(y[4], y[5], y[6], y[7]);
#pragma unroll
    for (int o = 32; o; o >>= 1) z += __shfl_xor(z, o);
    if (lane == 0) att[(size_t)b * 20 + v] = 1.f / (1.f + __expf(-(z + ba0)));
  }
  // maxpool over the 20 views
  for (int d = t; d < 512; d += 256) {
    float mx = -3.4e38f;
#pragma unroll
    for (int v = 0; v < 20; ++v) mx = fmaxf(mx, bf2f(xs[v * 512 + d]));
    fv2raw[(size_t)b * 512 + d] = f2bf(mx);
  }
}

// ---------- row-wise layernorm (4096 x 512 fp32 in) -> fp32 out + bf16 ws ----------
__global__ __launch_bounds__(256) void ln_rows(const float* __restrict__ in,
                                               const float* __restrict__ g,
                                               const float* __restrict__ bb,
                                               float* __restrict__ outF, u16* __restrict__ outB) {
  const int row = blockIdx.x * 4 + (threadIdx.x >> 6);
  const int lane = threadIdx.x & 63;
  const float* p = in + (size_t)row * 512 + lane * 8;
  float4 a = *(const float4*)p, c = *(const float4*)(p + 4);
  float f[8] = {a.x, a.y, a.z, a.w, c.x, c.y, c.z, c.w};
  float s = 0.f, ss = 0.f;
#pragma unroll
  for (int e = 0; e < 8; ++e) { s += f[e]; ss += f[e] * f[e]; }
#pragma unroll
  for (int o = 32; o; o >>= 1) { s += __shfl_xor(s, o); ss += __shfl_xor(ss, o); }
  const float m = s * (1.0f / 512.0f);
  const float rs = rsqrtf(ss * (1.0f / 512.0f) - m * m + 1e-5f);
  float y[8];
#pragma unroll
  for (int e = 0; e < 8; ++e) y[e] = (f[e] - m) * rs * g[lane * 8 + e] + bb[lane * 8 + e];
  float* op = outF + (size_t)row * 512 + lane * 8;
  *(float4*)op = make_float4(y[0], y[1], y[2], y[3]);
  *(float4*)(op + 4) = make_float4(y[4], y[5], y[6], y[7]);
  int4 ob = make_int4(pk2(y[0], y[1]), pk2(y[2], y[3]), pk2(y[4], y[5]), pk2(y[6], y[7]));
  *(int4*)(outB + (size_t)row * 512 + lane * 8) = ob;
}

// ---------- final small GEMM: [4096,256] bf16 @ [256,40] fp32 + bias ----------
__global__ __launch_bounds__(320) void pred_k(const u16* __restrict__ h2a,
                                              const float* __restrict__ W,
                                              const float* __restrict__ bias,
                                              float* __restrict__ out) {
  const int t = threadIdx.x;
  const int r = t / 40, n = t - r * 40;
  const size_t b = (size_t)blockIdx.x * 8 + r;
  const u16* hp = h2a + b * 256;
  float s = 0.f;
#pragma unroll 4
  for (int k0 = 0; k0 < 256; k0 += 8) {
    int4 q = *(const int4*)(hp + k0);
    float f0, f1, f2, f3, f4, f5, f6, f7;
    unpack2((unsigned)q.x, f0, f1);
    unpack2((unsigned)q.y, f2, f3);
    unpack2((unsigned)q.z, f4, f5);
    unpack2((unsigned)q.w, f6, f7);
    const float* wp = W + (size_t)k0 * 40 + n;
    s += f0 * wp[0] + f1 * wp[40] + f2 * wp[80] + f3 * wp[120] +
         f4 * wp[160] + f5 * wp[200] + f6 * wp[240] + f7 * wp[280];
  }
  out[b * 40 + n] = s + bias[n];
}

extern "C" void kernel_launch(void* const* d_in, const int* in_sizes, int n_in,
                              void* d_out, int out_size, void* d_ws, size_t ws_size,
                              hipStream_t stream) {
  (void)in_sizes; (void)n_in; (void)out_size; (void)ws_size;
  const float* x    = (const float*)d_in[0];
  const float* We   = (const float*)d_in[1];
  const float* be   = (const float*)d_in[2];
  const float* W1   = (const float*)d_in[3];
  const float* b1   = (const float*)d_in[4];
  const float* Wa   = (const float*)d_in[5];
  const float* ba   = (const float*)d_in[6];
  const float* W2   = (const float*)d_in[7];
  const float* b2   = (const float*)d_in[8];
  const float* ln_g = (const float*)d_in[9];
  const float* ln_b = (const float*)d_in[10];
  const float* h1W  = (const float*)d_in[11];
  const float* h1b  = (const float*)d_in[12];
  const float* bn1g = (const float*)d_in[13];
  const float* bn1b = (const float*)d_in[14];
  const float* h2W  = (const float*)d_in[15];
  const float* h2b  = (const float*)d_in[16];
  const float* bn2g = (const float*)d_in[17];
  const float* bn2b = (const float*)d_in[18];
  const float* h3W  = (const float*)d_in[19];
  const float* h3b  = (const float*)d_in[20];

  float* out = (float*)d_out;
  float* o_fcnn  = out;                    // 81920*512
  float* o_fvit1 = o_fcnn + 41943040;      // 81920*512
  float* o_att   = o_fvit1 + 41943040;     // 4096*20
  float* o_fvit2 = o_att + 81920;          // 4096*512
  float* o_fglob = o_fvit2 + 2097152;      // 4096*512
  float* o_pred  = o_fglob + 2097152;      // 4096*40

  // workspace layout (u16 units; all offsets 16B-aligned)
  u16* ws = (u16*)d_ws;
  u16* Wet   = ws;                   // 512*512
  u16* W1t   = Wet + 262144;         // 512*512
  u16* W2t   = W1t + 262144;         // 512*512
  u16* h1Wt  = W2t + 262144;         // 512*512
  u16* h2Wt  = h1Wt + 262144;        // 256*512
  u16* Wct   = h2Wt + 131072;        // 512*512  (We@W1)^T bf16
  u16* x1B   = Wct + 262144;         // 81920*512
  u16* fv2rB = x1B + 41943040;       // 4096*512
  u16* fv2B  = fv2rB + 2097152;      // 4096*512
  u16* hrelB = fv2B + 2097152;       // 4096*512
  u16* h2aB  = hrelB + 2097152;      // 4096*256
  float* bc    = (float*)(h2aB + 1048576);  // 512 fp32
  float* t3raw = bc + 512;                  // 4096*512 fp32

  const dim3 blk(256);
  // 1) transpose+cast weights
  transpose_w<<<dim3(16, 16), blk, 0, stream>>>(We, Wet, 512, 512);
  transpose_w<<<dim3(16, 16), blk, 0, stream>>>(W1, W1t, 512, 512);
  transpose_w<<<dim3(16, 16), blk, 0, stream>>>(W2, W2t, 512, 512);
  transpose_w<<<dim3(16, 16), blk, 0, stream>>>(h1W, h1Wt, 512, 512);
  transpose_w<<<dim3(8, 16), blk, 0, stream>>>(h2W, h2Wt, 512, 256);

  // 2) Wc^T = (We @ W1)^T  bf16  (MODE 7, fp32 A)
  gemm_k2<7, 4, 4, true><<<dim3(4, 4), blk, 0, stream>>>(
      We, nullptr, W1t, nullptr, nullptr, Wct, nullptr, nullptr, 512);
  // 3) bc = b1 + be @ W1
  bias_c<<<dim3(4), dim3(128), 0, stream>>>(be, W1, b1, bc);

  // 4) fused: f_cnn = x@We+be (fp32 out), x1 = x@Wc+bc (bf16 ws)
  gemm_x2<<<dim3(4, 640), blk, 0, stream>>>(x, Wet, Wct, be, bc, o_fcnn, x1B);

  // 5) f_vit1 = LN(x1), att = sigmoid(f_vit1@Wa+ba), fv2raw = max over views
  fuse_ln_att_max<<<dim3(4096), blk, 0, stream>>>(x1B, ln_g, ln_b, Wa, ba, o_fvit1, o_att, fv2rB);

  // 6) t3raw = fv2raw @ W2 + b2   (64x64 tiles, 512 blocks)
  gemm_k2<1, 2, 2, false><<<dim3(8, 64), blk, 0, stream>>>(
      nullptr, fv2rB, W2t, b2, t3raw, nullptr, nullptr, nullptr, 512);
  // 7) f_vit2 = LN(t3raw)
  ln_rows<<<dim3(1024), blk, 0, stream>>>(t3raw, ln_g, ln_b, o_fvit2, fv2B);
  // 8) f_global = bn1(f_vit2 @ h1W + h1b); hrelu = relu(f_global)
  gemm_k2<2, 2, 2, false><<<dim3(8, 64), blk, 0, stream>>>(
      nullptr, fv2B, h1Wt, h1b, o_fglob, hrelB, bn1g, bn1b, 512);
  // 9) h2 = relu(bn2(hrelu @ h2W + h2b))   (N=256)
  gemm_k2<3, 2, 2, false><<<dim3(4, 64), blk, 0, stream>>>(
      nullptr, hrelB, h2Wt, h2b, nullptr, h2aB, bn2g, bn2b, 256);
  // 10) pred = h2 @ h3W + h3b
  pred_k<<<dim3(512), dim3(320), 0, stream>>>(h2aB, h3W, h3b, o_pred);
}